// Round 13
// baseline (2472.191 us; speedup 1.0000x reference)
//
#include <hip/hip_runtime.h>
#include <hip/hip_bf16.h>

#define B_N 1024
#define H_N 256
#define O_N 128
#define D_N 64

// d_out offsets (f32 elements), reference tuple order
#define OFF_NEWH      0
#define OFF_NEWDELTA  262144
#define OFF_NEWINST   524288
#define OFF_NEWPJ     786432
#define OFF_NEWMEAN   67895296
#define OFF_NEWT      68157440
#define OFF_OUT       68158464
#define OFF_HCOPY     68289536
#define OFF_DELTAOUT  68551680
#define OFF_HNORM     68682752
#define OFF_DNORM     68683776
#define OFF_PJNORM    68684800
#define OFF_JAC       68685824

typedef __attribute__((ext_vector_type(8))) short short8;
typedef __attribute__((ext_vector_type(4))) float f32x4;

__device__ __forceinline__ short f2bf(float f){
  union { float f; unsigned u; } v; v.f = f;
  unsigned r = v.u + 0x7fffu + ((v.u >> 16) & 1u);
  return (short)(r >> 16);
}

__device__ __forceinline__ float wave_reduce_sum(float v){
  #pragma unroll
  for (int off = 32; off > 0; off >>= 1) v += __shfl_xor(v, off);
  return v;
}

// wave64 max-reduce via DPP (gfx9): ~6 VALU ops, result uniform via readlane.
__device__ __forceinline__ int wave_max_dpp(int v){
  int t;
  t = __builtin_amdgcn_update_dpp(v, v, 0x111, 0xf, 0xf, false); v = v > t ? v : t; // row_shr:1
  t = __builtin_amdgcn_update_dpp(v, v, 0x112, 0xf, 0xf, false); v = v > t ? v : t; // row_shr:2
  t = __builtin_amdgcn_update_dpp(v, v, 0x114, 0xf, 0xf, false); v = v > t ? v : t; // row_shr:4
  t = __builtin_amdgcn_update_dpp(v, v, 0x118, 0xf, 0xf, false); v = v > t ? v : t; // row_shr:8
  t = __builtin_amdgcn_update_dpp(v, v, 0x142, 0xf, 0xf, false); v = v > t ? v : t; // row_bcast:15
  t = __builtin_amdgcn_update_dpp(v, v, 0x143, 0xf, 0xf, false); v = v > t ? v : t; // row_bcast:31
  return __builtin_amdgcn_readlane(v, 63);
}

// ---------------------------------------------------------------------------
// Kernel 1: GRU gates, new_h, a-vectors, h copy, new_t, h_norm
// ---------------------------------------------------------------------------
__global__ __launch_bounds__(256) void gates_kernel(
    const float* __restrict__ x, const float* __restrict__ h, const float* __restrict__ tt,
    const float* __restrict__ Wiz, const float* __restrict__ biz, const float* __restrict__ Whz,
    const float* __restrict__ Wir, const float* __restrict__ bir, const float* __restrict__ Whr,
    const float* __restrict__ Win, const float* __restrict__ bin_, const float* __restrict__ Whn,
    const float* __restrict__ bhn,
    float* __restrict__ dout, float* __restrict__ ws)
{
  int b = blockIdx.x, j = threadIdx.x;
  __shared__ float xs[64];
  __shared__ float hs[256];
  __shared__ float red[4];
  if (j < 64) xs[j] = x[b*64 + j];
  float hj = h[b*256 + j];
  hs[j] = hj;
  __syncthreads();

  float zp = biz[j], rp = bir[j], np = bin_[j], g = bhn[j];
  #pragma unroll 8
  for (int k = 0; k < 64; k++){
    float xv = xs[k];
    zp = fmaf(xv, Wiz[k*256 + j], zp);
    rp = fmaf(xv, Wir[k*256 + j], rp);
    np = fmaf(xv, Win[k*256 + j], np);
  }
  #pragma unroll 8
  for (int k = 0; k < 256; k++){
    float hv = hs[k];
    zp = fmaf(hv, Whz[k*256 + j], zp);
    rp = fmaf(hv, Whr[k*256 + j], rp);
    g  = fmaf(hv, Whn[k*256 + j], g);
  }
  float r = 1.f / (1.f + expf(-rp));
  float z = 1.f / (1.f + expf(-zp));
  float n = tanhf(np + r*g);
  float nh = (1.f - z)*n + z*hj;

  float dz = z*(1.f - z);
  float dn = 1.f - n*n;
  float drv = r*(1.f - r);
  float az = (hj - n)*dz;
  float an = (1.f - z)*dn*r;
  float ar = (1.f - z)*dn*g*drv;

  dout[OFF_NEWH   + b*256 + j] = nh;
  dout[OFF_NEWMEAN+ b*256 + j] = nh;
  dout[OFF_HCOPY  + b*256 + j] = hj;
  ws[0*262144 + b*256 + j] = z;
  ws[1*262144 + b*256 + j] = az;
  ws[2*262144 + b*256 + j] = an;
  ws[3*262144 + b*256 + j] = ar;

  float s = wave_reduce_sum(nh*nh);
  if ((j & 63) == 0) red[j >> 6] = s;
  __syncthreads();
  if (j == 0){
    dout[OFF_HNORM + b] = sqrtf(red[0] + red[1] + red[2] + red[3]);
    dout[OFF_NEWT + b] = tt[b] + 1.f;
  }
}

// ---------------------------------------------------------------------------
// Kernel 2: build jac + BLOCKED (NB=8) Gauss-Jordan solve, partial pivoting.
// NEW vs R12: the panel factorization is no longer a single-wave serial phase
// (R12 PMC: VALUBusy 42% => panel ~ half of solve with 15/16 waves idle).
// ALL 16 waves factorize the panel REDUNDANTLY, 1 row/lane (P[8] = 8 regs --
// far below the 128-reg spill line; R10's 32-reg/lane variant spilled).
// Per pivot: local key -> per-wave DPP max -> 16 wave-maxes through LDS ->
// global max recomputed redundantly by every wave (deterministic: identical
// FP ops on identical data) -> pivot row's wc==0 copy publishes prowb[8] ->
// all lanes update their row.  2 barriers/pivot.  Single-writer discipline:
// scanb[w] by lane0 of each wave; prowb/D-rows/perm by wc==0 copies only.
// Trailing (unroll-1 -- the R8 spill fix), extraction, rhs-in-P_C (R11),
// dead-trailing-skip, double-buffered DT: unchanged, register-neutral.
// ---------------------------------------------------------------------------
__global__ __launch_bounds__(1024, 4) void solve_kernel(
    const float* __restrict__ Whz, const float* __restrict__ Whn, const float* __restrict__ Whr,
    const float* __restrict__ ws, const float* __restrict__ delta,
    const float* __restrict__ inst_delta, float* __restrict__ dout)
{
  const int b = blockIdx.x, tid = threadIdx.x;
  const int l  = tid & 63;
  const int w  = tid >> 6;           // 16 waves
  const int wr = w >> 2, wc = w & 3; // 4 x 4
  const int lr = l >> 3, lc = l & 7; // 8 x 8
  const int r0 = wr*64 + lr*8;       // first row of lane's 8-row tile
  const int c0 = wc*64 + lc*8;       // first col of lane's 8-col tile
  const int rowp = wr*64 + l;        // this lane's panel row in P_A

  __shared__ __align__(16) float DT[2][8*264];   // panel->D, double-buffered
  __shared__ __align__(16) float RB[8*264];      // pivot rows
  __shared__ __align__(16) float rhs[256];
  __shared__ __align__(16) float pivval_s[256];
  __shared__ int   perm_s[256];
  __shared__ int   scanb[16];
  __shared__ float prowb[8];

  // ---- build A tile (and write jac), in two 4-col halves (reg relief) ----
  float A[8][8];
  {
    float* jac_out = dout + OFF_JAC + (size_t)b*65536;
    #pragma unroll
    for (int half = 0; half < 2; half++){
      const int cb = c0 + half*4;
      float4 vz4 = *(const float4*)(ws + 0*262144 + b*256 + cb);
      float4 va4 = *(const float4*)(ws + 1*262144 + b*256 + cb);
      float4 vn4 = *(const float4*)(ws + 2*262144 + b*256 + cb);
      float4 vr4 = *(const float4*)(ws + 3*262144 + b*256 + cb);
      float zc[4] = {vz4.x, vz4.y, vz4.z, vz4.w};
      float az[4] = {va4.x, va4.y, va4.z, va4.w};
      float an[4] = {vn4.x, vn4.y, vn4.z, vn4.w};
      float ar[4] = {vr4.x, vr4.y, vr4.z, vr4.w};
      #pragma unroll
      for (int i = 0; i < 8; i++){
        const int row = r0 + i;
        float4 wz = *(const float4*)(Whz + row*256 + cb);
        float4 wn = *(const float4*)(Whn + row*256 + cb);
        float4 wq = *(const float4*)(Whr + row*256 + cb);
        A[i][half*4+0] = fmaf(wz.x, az[0], fmaf(wn.x, an[0], wq.x*ar[0]));
        A[i][half*4+1] = fmaf(wz.y, az[1], fmaf(wn.y, an[1], wq.y*ar[1]));
        A[i][half*4+2] = fmaf(wz.z, az[2], fmaf(wn.z, an[2], wq.z*ar[2]));
        A[i][half*4+3] = fmaf(wz.w, az[3], fmaf(wn.w, an[3], wq.w*ar[3]));
        #pragma unroll
        for (int k = 0; k < 4; k++)
          if (cb + k == row) A[i][half*4+k] += zc[k];
        *(float4*)(jac_out + row*256 + cb) =
            make_float4(A[i][half*4+0], A[i][half*4+1], A[i][half*4+2], A[i][half*4+3]);
      }
    }
  }

  if (tid < 256) rhs[tid] = delta[b*256 + tid] - inst_delta[b*256 + tid];

  // prologue: owners extract panel 0 into DT[0]
  if (wc == 0 && lc == 0){
    #pragma unroll
    for (int c = 0; c < 8; c++){
      *(float4*)&DT[0][c*264 + r0]     = make_float4(A[0][c], A[1][c], A[2][c], A[3][c]);
      *(float4*)&DT[0][c*264 + r0 + 4] = make_float4(A[4][c], A[5][c], A[6][c], A[7][c]);
    }
  }
  bool used = false;   // per lane: row `rowp` already pivoted (consistent
                       // across the 4 redundant wc-copies)
  __syncthreads();

  for (int kb = 0; kb < 32; kb++){
    const int cur = kb & 1;
    float* __restrict__ Dc = &DT[cur][0];      // panel kb -> becomes D_kb
    float* __restrict__ Dn = &DT[cur ^ 1][0];  // panel kb+1 written in P_C

    // ---- P_A: all-wave redundant panel factorization (1 row/lane) ----
    float P[8];
    #pragma unroll
    for (int c = 0; c < 8; c++) P[c] = Dc[c*264 + rowp];
    #pragma unroll 1
    for (int j = 0; j < 8; j++){
      unsigned key = used ? 0u
          : ((__float_as_uint(fabsf(P[j])) & 0xFFFFFF00u) | (unsigned)rowp);
      int wmax = wave_max_dpp((int)key);
      if (l == 0) scanb[w] = wmax;
      __syncthreads();                       // S1
      int g = scanb[0];
      #pragma unroll
      for (int i = 1; i < 16; i++){ int sv = scanb[i]; g = sv > g ? sv : g; }
      const int p = g & 255;
      if (wc == 0 && rowp == p){
        #pragma unroll
        for (int c = 0; c < 8; c++) prowb[c] = P[c];
      }
      __syncthreads();                       // S2
      float prow[8];
      #pragma unroll
      for (int c = 0; c < 8; c++) prow[c] = prowb[c];
      const float pv = prow[j];
      const float ipv = 1.0f / pv;
      const bool own = (rowp == p);
      if (own) used = true;
      const float d = own ? 0.f : P[j] * ipv;
      #pragma unroll
      for (int c = 0; c < 8; c++){
        if (c == j) continue;
        P[c] = fmaf(-d, prow[c], P[c]);
      }
      P[j] = d;
      if (tid == 0){ perm_s[kb*8 + j] = p; pivval_s[kb*8 + j] = pv; }
    }
    // write D rows (single writer per row: the wc==0 copies)
    if (wc == 0){
      #pragma unroll
      for (int c = 0; c < 8; c++) Dc[c*264 + rowp] = P[c];
    }
    __syncthreads();   // B1

    // ---- P_B: extract pivot rows kb -> RB ; gather rhsP ----
    int pq8[8];
    #pragma unroll
    for (int q = 0; q < 8; q++) pq8[q] = perm_s[kb*8 + q];
    #pragma unroll
    for (int i = 0; i < 8; i++){
      int qm = -1;
      #pragma unroll
      for (int q = 0; q < 8; q++) qm = (pq8[q] == r0 + i) ? q : qm;
      if (qm >= 0){
        *(float4*)&RB[qm*264 + c0]     = make_float4(A[i][0], A[i][1], A[i][2], A[i][3]);
        *(float4*)&RB[qm*264 + c0 + 4] = make_float4(A[i][4], A[i][5], A[i][6], A[i][7]);
      }
    }
    float rhsP[8];
    if (tid < 256){
      #pragma unroll
      for (int q = 0; q < 8; q++) rhsP[q] = rhs[pq8[q]];
    }
    __syncthreads();   // B2

    // ---- P_C: trailing(kb) (skip dead kb=31), owners extract kb+1 -> Dn,
    //      rhs update ----
    if (kb < 31){
      #pragma unroll 1
      for (int q = 0; q < 8; q++){
        float4 d0 = *(const float4*)&Dc[q*264 + r0];
        float4 d1 = *(const float4*)&Dc[q*264 + r0 + 4];
        float4 ra = *(const float4*)&RB[q*264 + c0];
        float4 rb4 = *(const float4*)&RB[q*264 + c0 + 4];
        float dq[8] = {d0.x, d0.y, d0.z, d0.w, d1.x, d1.y, d1.z, d1.w};
        float rq[8] = {ra.x, ra.y, ra.z, ra.w, rb4.x, rb4.y, rb4.z, rb4.w};
        #pragma unroll
        for (int i = 0; i < 8; i++)
          #pragma unroll
          for (int j = 0; j < 8; j++)
            A[i][j] = fmaf(-dq[i], rq[j], A[i][j]);
      }
      // owners of panel kb+1 extract it (their A is updated through kb now)
      if (wc == ((kb+1) >> 3) && lc == ((kb+1) & 7)){
        #pragma unroll
        for (int c = 0; c < 8; c++){
          *(float4*)&Dn[c*264 + r0]     = make_float4(A[0][c], A[1][c], A[2][c], A[3][c]);
          *(float4*)&Dn[c*264 + r0 + 4] = make_float4(A[4][c], A[5][c], A[6][c], A[7][c]);
        }
      }
    }
    if (tid < 256){
      float rv = rhs[tid];
      #pragma unroll 1
      for (int q = 0; q < 8; q++) rv = fmaf(-Dc[q*264 + tid], rhsP[q], rv);
      rhs[tid] = rv;
    }
    __syncthreads();   // B3
  }

  if (tid < 256){
    float xv = rhs[perm_s[tid]] / pivval_s[tid];
    dout[OFF_NEWDELTA + b*256 + tid] = xv;
    RB[tid] = xv*xv;
  }
  __syncthreads();
  if (tid < 64){
    float s = RB[tid] + RB[tid+64] + RB[tid+128] + RB[tid+192];
    s = wave_reduce_sum(s);
    if (tid == 0) dout[OFF_DNORM + b] = sqrtf(s);
  }
}

// ---------------------------------------------------------------------------
// Kernel 3: new_prod_jac[b] = prod_jac[b] @ jac[b]  (bf16 MFMA, f32 LDS pad-33)
// one block (512 thr, 8 waves as 2x4) per batch; + Frobenius norm epilogue
// ---------------------------------------------------------------------------
__global__ __launch_bounds__(512) void pj_gemm_kernel(
    const float* __restrict__ prod_jac, const float* __restrict__ jac,
    float* __restrict__ out_pj, float* __restrict__ out_norm)
{
  int b = blockIdx.x, tid = threadIdx.x;
  int l = tid & 63, wid = tid >> 6;
  int wm = wid >> 2, wn = wid & 3;
  int lr = l & 15, lg = l >> 4;

  __shared__ float As[256*33];
  __shared__ float Bs[256*33];

  const float* Ag = prod_jac + (size_t)b*65536;
  const float* Bg = jac      + (size_t)b*65536;

  f32x4 acc[8][4];
  #pragma unroll
  for (int i = 0; i < 8; i++)
    #pragma unroll
    for (int jn = 0; jn < 4; jn++) acc[i][jn] = (f32x4){0.f,0.f,0.f,0.f};

  const int arow = tid >> 1, acolb = (tid & 1)*16;
  const int bk = tid >> 4, bcolb = (tid & 15)*16;

  for (int kt = 0; kt < 8; ++kt){
    const int k0 = kt*32;
    __syncthreads();
    {
      const float4* asrc = (const float4*)(Ag + arow*256 + k0 + acolb);
      float* ad = &As[arow*33 + acolb];
      #pragma unroll
      for (int q = 0; q < 4; q++){
        float4 v = asrc[q];
        ad[q*4+0]=v.x; ad[q*4+1]=v.y; ad[q*4+2]=v.z; ad[q*4+3]=v.w;
      }
      const float4* bsrc = (const float4*)(Bg + (k0 + bk)*256 + bcolb);
      #pragma unroll
      for (int q = 0; q < 4; q++){
        float4 v = bsrc[q];
        Bs[(bcolb+q*4+0)*33 + bk] = v.x;
        Bs[(bcolb+q*4+1)*33 + bk] = v.y;
        Bs[(bcolb+q*4+2)*33 + bk] = v.z;
        Bs[(bcolb+q*4+3)*33 + bk] = v.w;
      }
    }
    __syncthreads();

    short8 bfr[4];
    #pragma unroll
    for (int ni = 0; ni < 4; ni++){
      const float* bp = &Bs[(wn*64 + ni*16 + lr)*33 + lg*8];
      short8 t;
      #pragma unroll
      for (int v = 0; v < 8; v++) t[v] = f2bf(bp[v]);
      bfr[ni] = t;
    }
    #pragma unroll
    for (int mi = 0; mi < 8; mi++){
      const float* ap = &As[(wm*128 + mi*16 + lr)*33 + lg*8];
      short8 af;
      #pragma unroll
      for (int v = 0; v < 8; v++) af[v] = f2bf(ap[v]);
      #pragma unroll
      for (int ni = 0; ni < 4; ni++)
        acc[mi][ni] = __builtin_amdgcn_mfma_f32_16x16x32_bf16(af, bfr[ni], acc[mi][ni], 0, 0, 0);
    }
  }

  float nrm = 0.f;
  #pragma unroll
  for (int mi = 0; mi < 8; mi++){
    #pragma unroll
    for (int ni = 0; ni < 4; ni++){
      #pragma unroll
      for (int rr = 0; rr < 4; rr++){
        int row = wm*128 + mi*16 + lg*4 + rr;
        int col = wn*64 + ni*16 + lr;
        float vv = acc[mi][ni][rr];
        out_pj[(size_t)b*65536 + row*256 + col] = vv;
        nrm += vv*vv;
      }
    }
  }
  __syncthreads();
  As[tid] = nrm;
  __syncthreads();
  if (tid < 64){
    float s = 0.f;
    #pragma unroll
    for (int q = 0; q < 8; q++) s += As[tid + q*64];
    s = wave_reduce_sum(s);
    if (tid == 0) out_norm[b] = sqrtf(s);
  }
}

// ---------------------------------------------------------------------------
// Kernel 4: readout (LayerNorm + Wout), out, delta_output, LN-VJP inst_delta
// ---------------------------------------------------------------------------
__global__ __launch_bounds__(256) void readout_kernel(
    const float* __restrict__ y, const float* __restrict__ m,
    const float* __restrict__ ln_scale, const float* __restrict__ ln_bias,
    const float* __restrict__ Wout, const float* __restrict__ bout,
    float* __restrict__ dout)
{
  int b = blockIdx.x, j = threadIdx.x;
  __shared__ float lno[256], xh[256], go[128], red2[256], red[4];

  float hv = dout[OFF_NEWH + b*256 + j];
  float s = wave_reduce_sum(hv);
  if ((j & 63) == 0) red[j >> 6] = s;
  __syncthreads();
  float mu = (red[0] + red[1] + red[2] + red[3]) * (1.f/256.f);
  __syncthreads();
  float d = hv - mu;
  float sv = wave_reduce_sum(d*d);
  if ((j & 63) == 0) red[j >> 6] = sv;
  __syncthreads();
  float var = (red[0] + red[1] + red[2] + red[3]) * (1.f/256.f);
  float rstd = rsqrtf(var + 1e-6f);
  float xhj = d * rstd;
  xh[j] = xhj;
  lno[j] = xhj * ln_scale[j] + ln_bias[j];
  __syncthreads();

  // forward o = lno @ Wout + bout, split across thread halves
  int i = j & 127, half = j >> 7;
  float part = half ? 0.f : bout[i];
  #pragma unroll 8
  for (int jj = half*128; jj < half*128 + 128; jj++)
    part = fmaf(lno[jj], Wout[jj*128 + i], part);
  red2[j] = part;
  __syncthreads();
  if (j < 128){
    float o = red2[j] + red2[j + 128];
    float gv = 2.f * m[b*128 + j] * (o - y[b*128 + j]);
    dout[OFF_OUT + b*128 + j] = o;
    dout[OFF_DELTAOUT + b*128 + j] = gv;
    go[j] = gv;
  }
  __syncthreads();

  // backward through Wout and LayerNorm
  float gl = 0.f;
  const float4* wrow = (const float4*)(Wout + j*128);
  #pragma unroll 8
  for (int q = 0; q < 32; q++){
    float4 w = wrow[q];
    gl = fmaf(w.x, go[q*4+0], gl);
    gl = fmaf(w.y, go[q*4+1], gl);
    gl = fmaf(w.z, go[q*4+2], gl);
    gl = fmaf(w.w, go[q*4+3], gl);
  }
  float gx = gl * ln_scale[j];
  __syncthreads();
  float t1 = wave_reduce_sum(gx);
  if ((j & 63) == 0) red[j >> 6] = t1;
  __syncthreads();
  float s1 = (red[0] + red[1] + red[2] + red[3]) * (1.f/256.f);
  __syncthreads();
  float t2 = wave_reduce_sum(gx * xhj);
  if ((j & 63) == 0) red[j >> 6] = t2;
  __syncthreads();
  float s2m = (red[0] + red[1] + red[2] + red[3]) * (1.f/256.f);
  float nid = rstd * (gx - s1 - xhj * s2m);
  dout[OFF_NEWINST + b*256 + j] = nid;
}

// ---------------------------------------------------------------------------
extern "C" void kernel_launch(void* const* d_in, const int* in_sizes, int n_in,
                              void* d_out, int out_size, void* d_ws, size_t ws_size,
                              hipStream_t stream) {
  const float* x          = (const float*)d_in[0];
  const float* y          = (const float*)d_in[1];
  const float* m          = (const float*)d_in[2];
  const float* h          = (const float*)d_in[3];
  const float* delta      = (const float*)d_in[4];
  const float* inst_delta = (const float*)d_in[5];
  const float* prod_jac   = (const float*)d_in[6];
  const float* t          = (const float*)d_in[8];
  const float* Wiz  = (const float*)d_in[9];
  const float* biz  = (const float*)d_in[10];
  const float* Whz  = (const float*)d_in[11];
  const float* Wir  = (const float*)d_in[12];
  const float* bir  = (const float*)d_in[13];
  const float* Whr  = (const float*)d_in[14];
  const float* Win  = (const float*)d_in[15];
  const float* bin_ = (const float*)d_in[16];
  const float* Whn  = (const float*)d_in[17];
  const float* bhn  = (const float*)d_in[18];
  const float* ln_scale = (const float*)d_in[19];
  const float* ln_bias  = (const float*)d_in[20];
  const float* Wout = (const float*)d_in[21];
  const float* bout = (const float*)d_in[22];

  float* dout = (float*)d_out;
  float* ws = (float*)d_ws;

  gates_kernel<<<1024, 256, 0, stream>>>(x, h, t, Wiz, biz, Whz, Wir, bir, Whr,
                                         Win, bin_, Whn, bhn, dout, ws);
  solve_kernel<<<1024, 1024, 0, stream>>>(Whz, Whn, Whr, ws, delta, inst_delta, dout);
  pj_gemm_kernel<<<1024, 512, 0, stream>>>(prod_jac, dout + OFF_JAC,
                                           dout + OFF_NEWPJ, dout + OFF_PJNORM);
  readout_kernel<<<1024, 256, 0, stream>>>(y, m, ln_scale, ln_bias, Wout, bout, dout);
}

// Round 14
// 1610.440 us; speedup vs baseline: 1.5351x; 1.5351x over previous
//
#include <hip/hip_runtime.h>
#include <hip/hip_bf16.h>

#define B_N 1024
#define H_N 256
#define O_N 128
#define D_N 64

// d_out offsets (f32 elements), reference tuple order
#define OFF_NEWH      0
#define OFF_NEWDELTA  262144
#define OFF_NEWINST   524288
#define OFF_NEWPJ     786432
#define OFF_NEWMEAN   67895296
#define OFF_NEWT      68157440
#define OFF_OUT       68158464
#define OFF_HCOPY     68289536
#define OFF_DELTAOUT  68551680
#define OFF_HNORM     68682752
#define OFF_DNORM     68683776
#define OFF_PJNORM    68684800
#define OFF_JAC       68685824

typedef __attribute__((ext_vector_type(8))) short short8;
typedef __attribute__((ext_vector_type(4))) float f32x4;

__device__ __forceinline__ short f2bf(float f){
  union { float f; unsigned u; } v; v.f = f;
  unsigned r = v.u + 0x7fffu + ((v.u >> 16) & 1u);
  return (short)(r >> 16);
}

__device__ __forceinline__ float wave_reduce_sum(float v){
  #pragma unroll
  for (int off = 32; off > 0; off >>= 1) v += __shfl_xor(v, off);
  return v;
}

// wave64 max-reduce via DPP (gfx9): ~6 VALU ops, result uniform via readlane.
// Every input key is pre-masked for freshness, so any max-combination of keys
// is a valid fresh candidate.
__device__ __forceinline__ int wave_max_dpp(int v){
  int t;
  t = __builtin_amdgcn_update_dpp(v, v, 0x111, 0xf, 0xf, false); v = v > t ? v : t; // row_shr:1
  t = __builtin_amdgcn_update_dpp(v, v, 0x112, 0xf, 0xf, false); v = v > t ? v : t; // row_shr:2
  t = __builtin_amdgcn_update_dpp(v, v, 0x114, 0xf, 0xf, false); v = v > t ? v : t; // row_shr:4
  t = __builtin_amdgcn_update_dpp(v, v, 0x118, 0xf, 0xf, false); v = v > t ? v : t; // row_shr:8
  t = __builtin_amdgcn_update_dpp(v, v, 0x142, 0xf, 0xf, false); v = v > t ? v : t; // row_bcast:15
  t = __builtin_amdgcn_update_dpp(v, v, 0x143, 0xf, 0xf, false); v = v > t ? v : t; // row_bcast:31
  return __builtin_amdgcn_readlane(v, 63);
}

// ---------------------------------------------------------------------------
// Kernel 1: GRU gates, new_h, a-vectors, h copy, new_t, h_norm
// ---------------------------------------------------------------------------
__global__ __launch_bounds__(256) void gates_kernel(
    const float* __restrict__ x, const float* __restrict__ h, const float* __restrict__ tt,
    const float* __restrict__ Wiz, const float* __restrict__ biz, const float* __restrict__ Whz,
    const float* __restrict__ Wir, const float* __restrict__ bir, const float* __restrict__ Whr,
    const float* __restrict__ Win, const float* __restrict__ bin_, const float* __restrict__ Whn,
    const float* __restrict__ bhn,
    float* __restrict__ dout, float* __restrict__ ws)
{
  int b = blockIdx.x, j = threadIdx.x;
  __shared__ float xs[64];
  __shared__ float hs[256];
  __shared__ float red[4];
  if (j < 64) xs[j] = x[b*64 + j];
  float hj = h[b*256 + j];
  hs[j] = hj;
  __syncthreads();

  float zp = biz[j], rp = bir[j], np = bin_[j], g = bhn[j];
  #pragma unroll 8
  for (int k = 0; k < 64; k++){
    float xv = xs[k];
    zp = fmaf(xv, Wiz[k*256 + j], zp);
    rp = fmaf(xv, Wir[k*256 + j], rp);
    np = fmaf(xv, Win[k*256 + j], np);
  }
  #pragma unroll 8
  for (int k = 0; k < 256; k++){
    float hv = hs[k];
    zp = fmaf(hv, Whz[k*256 + j], zp);
    rp = fmaf(hv, Whr[k*256 + j], rp);
    g  = fmaf(hv, Whn[k*256 + j], g);
  }
  float r = 1.f / (1.f + expf(-rp));
  float z = 1.f / (1.f + expf(-zp));
  float n = tanhf(np + r*g);
  float nh = (1.f - z)*n + z*hj;

  float dz = z*(1.f - z);
  float dn = 1.f - n*n;
  float drv = r*(1.f - r);
  float az = (hj - n)*dz;
  float an = (1.f - z)*dn*r;
  float ar = (1.f - z)*dn*g*drv;

  dout[OFF_NEWH   + b*256 + j] = nh;
  dout[OFF_NEWMEAN+ b*256 + j] = nh;
  dout[OFF_HCOPY  + b*256 + j] = hj;
  ws[0*262144 + b*256 + j] = z;
  ws[1*262144 + b*256 + j] = az;
  ws[2*262144 + b*256 + j] = an;
  ws[3*262144 + b*256 + j] = ar;

  float s = wave_reduce_sum(nh*nh);
  if ((j & 63) == 0) red[j >> 6] = s;
  __syncthreads();
  if (j == 0){
    dout[OFF_HNORM + b] = sqrtf(red[0] + red[1] + red[2] + red[3]);
    dout[OFF_NEWT + b] = tt[b] + 1.f;
  }
}

// ---------------------------------------------------------------------------
// Kernel 2: build jac + BLOCKED (NB=8) Gauss-Jordan solve, partial pivoting.
// BEST-KNOWN CONFIG (R12: solve 1453us).  Structure: wave0 serial in-LDS
// panel factorization (carried current-column) + DPP pivot scan + setprio,
// rhs-update overlapped on waves 4-7 during P_A, unroll-1 rank-8 trailing
// (full unroll spills A), owners-extract into double-buffered DT, 3 barriers
// per iteration, dead trailing(31) skipped.
// Measured dead-ends (do NOT revisit):
//  - R9  pipeline panel||trailing: -13% (wave0 owns an A-tile either way)
//  - R10 panel in wave0 registers: spill (>128 live regs, 3.5GB scratch)
//  - R13 all-wave redundant panel: -63% (16 block barriers/iter @~1300cyc)
// ---------------------------------------------------------------------------
__global__ __launch_bounds__(1024, 4) void solve_kernel(
    const float* __restrict__ Whz, const float* __restrict__ Whn, const float* __restrict__ Whr,
    const float* __restrict__ ws, const float* __restrict__ delta,
    const float* __restrict__ inst_delta, float* __restrict__ dout)
{
  const int b = blockIdx.x, tid = threadIdx.x;
  const int l  = tid & 63;
  const int w  = tid >> 6;           // 16 waves
  const int wr = w >> 2, wc = w & 3; // 4 x 4
  const int lr = l >> 3, lc = l & 7; // 8 x 8
  const int r0 = wr*64 + lr*8;       // first row of lane's 8-row tile
  const int c0 = wc*64 + lc*8;       // first col of lane's 8-col tile

  __shared__ __align__(16) float DT[2][8*264];   // panel->D, double-buffered
  __shared__ __align__(16) float RB[8*264];      // pivot rows
  __shared__ __align__(16) float rhs[256];
  __shared__ __align__(16) float pivval_s[256];
  __shared__ int   perm_s[256];

  // ---- build A tile (and write jac), in two 4-col halves (reg relief) ----
  float A[8][8];
  {
    float* jac_out = dout + OFF_JAC + (size_t)b*65536;
    #pragma unroll
    for (int half = 0; half < 2; half++){
      const int cb = c0 + half*4;
      float4 vz4 = *(const float4*)(ws + 0*262144 + b*256 + cb);
      float4 va4 = *(const float4*)(ws + 1*262144 + b*256 + cb);
      float4 vn4 = *(const float4*)(ws + 2*262144 + b*256 + cb);
      float4 vr4 = *(const float4*)(ws + 3*262144 + b*256 + cb);
      float zc[4] = {vz4.x, vz4.y, vz4.z, vz4.w};
      float az[4] = {va4.x, va4.y, va4.z, va4.w};
      float an[4] = {vn4.x, vn4.y, vn4.z, vn4.w};
      float ar[4] = {vr4.x, vr4.y, vr4.z, vr4.w};
      #pragma unroll
      for (int i = 0; i < 8; i++){
        const int row = r0 + i;
        float4 wz = *(const float4*)(Whz + row*256 + cb);
        float4 wn = *(const float4*)(Whn + row*256 + cb);
        float4 wq = *(const float4*)(Whr + row*256 + cb);
        A[i][half*4+0] = fmaf(wz.x, az[0], fmaf(wn.x, an[0], wq.x*ar[0]));
        A[i][half*4+1] = fmaf(wz.y, az[1], fmaf(wn.y, an[1], wq.y*ar[1]));
        A[i][half*4+2] = fmaf(wz.z, az[2], fmaf(wn.z, an[2], wq.z*ar[2]));
        A[i][half*4+3] = fmaf(wz.w, az[3], fmaf(wn.w, an[3], wq.w*ar[3]));
        #pragma unroll
        for (int k = 0; k < 4; k++)
          if (cb + k == row) A[i][half*4+k] += zc[k];
        *(float4*)(jac_out + row*256 + cb) =
            make_float4(A[i][half*4+0], A[i][half*4+1], A[i][half*4+2], A[i][half*4+3]);
      }
    }
  }

  if (tid < 256) rhs[tid] = delta[b*256 + tid] - inst_delta[b*256 + tid];

  // prologue: owners extract panel 0 into DT[0]
  if (wc == 0 && lc == 0){
    #pragma unroll
    for (int c = 0; c < 8; c++){
      *(float4*)&DT[0][c*264 + r0]     = make_float4(A[0][c], A[1][c], A[2][c], A[3][c]);
      *(float4*)&DT[0][c*264 + r0 + 4] = make_float4(A[4][c], A[5][c], A[6][c], A[7][c]);
    }
  }
  unsigned usedbits = 0u;  // wave0: rows 4l..4l+3 already pivoted
  float rhsP[8];           // live in threads 256..511 across phases
  __syncthreads();

  for (int kb = 0; kb < 32; kb++){
    const int cur = kb & 1;
    float* __restrict__ Dc = &DT[cur][0];      // panel kb -> becomes D_kb
    float* __restrict__ Dn = &DT[cur ^ 1][0];  // D_{kb-1} now; panel kb+1 in P_C

    // ---- P_A: wave0 factorizes panel kb (high prio) || waves 4-7 do the
    //      rhs update for block kb-1 ----
    if (w == 0){
      __builtin_amdgcn_s_setprio(1);
      float4 curc = *(const float4*)&Dc[0*264 + 4*l];
      #pragma unroll
      for (int j = 0; j < 8; j++){
        float c4[4] = {curc.x, curc.y, curc.z, curc.w};
        unsigned key = 0u;
        #pragma unroll
        for (int q = 0; q < 4; q++){
          unsigned kq = (__float_as_uint(fabsf(c4[q])) & 0xFFFFFF00u) | (unsigned)(l*4 + q);
          bool fresh = ((usedbits >> q) & 1u) == 0u;
          key = (fresh && kq > key) ? kq : key;
        }
        const int p = wave_max_dpp((int)key) & 255;
        float sel = c4[0];
        #pragma unroll
        for (int q = 1; q < 4; q++) sel = ((p & 3) == q) ? c4[q] : sel;
        const float pv = __shfl(sel, p >> 2);
        const float ipv = 1.0f / pv;
        if ((p >> 2) == l) usedbits |= 1u << (p & 3);
        const bool own = ((p >> 2) == l);
        float d4[4];
        #pragma unroll
        for (int q = 0; q < 4; q++){
          float dv = c4[q] * ipv;
          d4[q] = (own && (p & 3) == q) ? 0.f : dv;
        }
        float prow[8];
        #pragma unroll
        for (int c = 0; c < 8; c++) prow[c] = Dc[c*264 + p];
        #pragma unroll
        for (int c = 0; c < 8; c++){
          if (c == j){
            *(float4*)&Dc[j*264 + 4*l] = make_float4(d4[0], d4[1], d4[2], d4[3]);
          } else {
            float4 pc = *(const float4*)&Dc[c*264 + 4*l];
            pc.x = fmaf(-d4[0], prow[c], pc.x);
            pc.y = fmaf(-d4[1], prow[c], pc.y);
            pc.z = fmaf(-d4[2], prow[c], pc.z);
            pc.w = fmaf(-d4[3], prow[c], pc.w);
            if (c == j + 1) curc = pc;                // carried; skip LDS write
            else *(float4*)&Dc[c*264 + 4*l] = pc;
          }
        }
        if (l == 0){ perm_s[kb*8 + j] = p; pivval_s[kb*8 + j] = pv; }
      }
      __builtin_amdgcn_s_setprio(0);
    }
    if (kb > 0 && tid >= 256 && tid < 512){
      const int e = tid - 256;
      float rv = rhs[e];
      #pragma unroll 1
      for (int q = 0; q < 8; q++) rv = fmaf(-Dn[q*264 + e], rhsP[q], rv);
      rhs[e] = rv;
    }
    __syncthreads();   // B1

    // ---- P_B: extract pivot rows kb -> RB ; gather rhsP (threads 256-511) --
    int pq8[8];
    #pragma unroll
    for (int q = 0; q < 8; q++) pq8[q] = perm_s[kb*8 + q];
    #pragma unroll
    for (int i = 0; i < 8; i++){
      int qm = -1;
      #pragma unroll
      for (int q = 0; q < 8; q++) qm = (pq8[q] == r0 + i) ? q : qm;
      if (qm >= 0){
        *(float4*)&RB[qm*264 + c0]     = make_float4(A[i][0], A[i][1], A[i][2], A[i][3]);
        *(float4*)&RB[qm*264 + c0 + 4] = make_float4(A[i][4], A[i][5], A[i][6], A[i][7]);
      }
    }
    if (tid >= 256 && tid < 512){
      #pragma unroll
      for (int q = 0; q < 8; q++) rhsP[q] = rhs[pq8[q]];
    }
    __syncthreads();   // B2

    // ---- P_C: trailing(kb) (skip dead kb=31), owners extract kb+1 -> Dn ----
    if (kb < 31){
      #pragma unroll 1
      for (int q = 0; q < 8; q++){
        float4 d0 = *(const float4*)&Dc[q*264 + r0];
        float4 d1 = *(const float4*)&Dc[q*264 + r0 + 4];
        float4 ra = *(const float4*)&RB[q*264 + c0];
        float4 rb4 = *(const float4*)&RB[q*264 + c0 + 4];
        float dq[8] = {d0.x, d0.y, d0.z, d0.w, d1.x, d1.y, d1.z, d1.w};
        float rq[8] = {ra.x, ra.y, ra.z, ra.w, rb4.x, rb4.y, rb4.z, rb4.w};
        #pragma unroll
        for (int i = 0; i < 8; i++)
          #pragma unroll
          for (int j = 0; j < 8; j++)
            A[i][j] = fmaf(-dq[i], rq[j], A[i][j]);
      }
      // owners of panel kb+1 extract it (their A is updated through kb now)
      if (wc == ((kb+1) >> 3) && lc == ((kb+1) & 7)){
        #pragma unroll
        for (int c = 0; c < 8; c++){
          *(float4*)&Dn[c*264 + r0]     = make_float4(A[0][c], A[1][c], A[2][c], A[3][c]);
          *(float4*)&Dn[c*264 + r0 + 4] = make_float4(A[4][c], A[5][c], A[6][c], A[7][c]);
        }
      }
    }
    __syncthreads();   // B3
  }

  // epilogue: final rhs update (kb=31; D_31 lives in DT[1])
  if (tid >= 256 && tid < 512){
    const int e = tid - 256;
    float rv = rhs[e];
    #pragma unroll 1
    for (int q = 0; q < 8; q++) rv = fmaf(-DT[1][q*264 + e], rhsP[q], rv);
    rhs[e] = rv;
  }
  __syncthreads();

  if (tid < 256){
    float xv = rhs[perm_s[tid]] / pivval_s[tid];
    dout[OFF_NEWDELTA + b*256 + tid] = xv;
    RB[tid] = xv*xv;
  }
  __syncthreads();
  if (tid < 64){
    float s = RB[tid] + RB[tid+64] + RB[tid+128] + RB[tid+192];
    s = wave_reduce_sum(s);
    if (tid == 0) dout[OFF_DNORM + b] = sqrtf(s);
  }
}

// ---------------------------------------------------------------------------
// Kernel 3: new_prod_jac[b] = prod_jac[b] @ jac[b]  (bf16 MFMA, f32 LDS pad-33)
// one block (512 thr, 8 waves as 2x4) per batch; + Frobenius norm epilogue
// ---------------------------------------------------------------------------
__global__ __launch_bounds__(512) void pj_gemm_kernel(
    const float* __restrict__ prod_jac, const float* __restrict__ jac,
    float* __restrict__ out_pj, float* __restrict__ out_norm)
{
  int b = blockIdx.x, tid = threadIdx.x;
  int l = tid & 63, wid = tid >> 6;
  int wm = wid >> 2, wn = wid & 3;
  int lr = l & 15, lg = l >> 4;

  __shared__ float As[256*33];
  __shared__ float Bs[256*33];

  const float* Ag = prod_jac + (size_t)b*65536;
  const float* Bg = jac      + (size_t)b*65536;

  f32x4 acc[8][4];
  #pragma unroll
  for (int i = 0; i < 8; i++)
    #pragma unroll
    for (int jn = 0; jn < 4; jn++) acc[i][jn] = (f32x4){0.f,0.f,0.f,0.f};

  const int arow = tid >> 1, acolb = (tid & 1)*16;
  const int bk = tid >> 4, bcolb = (tid & 15)*16;

  for (int kt = 0; kt < 8; ++kt){
    const int k0 = kt*32;
    __syncthreads();
    {
      const float4* asrc = (const float4*)(Ag + arow*256 + k0 + acolb);
      float* ad = &As[arow*33 + acolb];
      #pragma unroll
      for (int q = 0; q < 4; q++){
        float4 v = asrc[q];
        ad[q*4+0]=v.x; ad[q*4+1]=v.y; ad[q*4+2]=v.z; ad[q*4+3]=v.w;
      }
      const float4* bsrc = (const float4*)(Bg + (k0 + bk)*256 + bcolb);
      #pragma unroll
      for (int q = 0; q < 4; q++){
        float4 v = bsrc[q];
        Bs[(bcolb+q*4+0)*33 + bk] = v.x;
        Bs[(bcolb+q*4+1)*33 + bk] = v.y;
        Bs[(bcolb+q*4+2)*33 + bk] = v.z;
        Bs[(bcolb+q*4+3)*33 + bk] = v.w;
      }
    }
    __syncthreads();

    short8 bfr[4];
    #pragma unroll
    for (int ni = 0; ni < 4; ni++){
      const float* bp = &Bs[(wn*64 + ni*16 + lr)*33 + lg*8];
      short8 t;
      #pragma unroll
      for (int v = 0; v < 8; v++) t[v] = f2bf(bp[v]);
      bfr[ni] = t;
    }
    #pragma unroll
    for (int mi = 0; mi < 8; mi++){
      const float* ap = &As[(wm*128 + mi*16 + lr)*33 + lg*8];
      short8 af;
      #pragma unroll
      for (int v = 0; v < 8; v++) af[v] = f2bf(ap[v]);
      #pragma unroll
      for (int ni = 0; ni < 4; ni++)
        acc[mi][ni] = __builtin_amdgcn_mfma_f32_16x16x32_bf16(af, bfr[ni], acc[mi][ni], 0, 0, 0);
    }
  }

  float nrm = 0.f;
  #pragma unroll
  for (int mi = 0; mi < 8; mi++){
    #pragma unroll
    for (int ni = 0; ni < 4; ni++){
      #pragma unroll
      for (int rr = 0; rr < 4; rr++){
        int row = wm*128 + mi*16 + lg*4 + rr;
        int col = wn*64 + ni*16 + lr;
        float vv = acc[mi][ni][rr];
        out_pj[(size_t)b*65536 + row*256 + col] = vv;
        nrm += vv*vv;
      }
    }
  }
  __syncthreads();
  As[tid] = nrm;
  __syncthreads();
  if (tid < 64){
    float s = 0.f;
    #pragma unroll
    for (int q = 0; q < 8; q++) s += As[tid + q*64];
    s = wave_reduce_sum(s);
    if (tid == 0) out_norm[b] = sqrtf(s);
  }
}

// ---------------------------------------------------------------------------
// Kernel 4: readout (LayerNorm + Wout), out, delta_output, LN-VJP inst_delta
// ---------------------------------------------------------------------------
__global__ __launch_bounds__(256) void readout_kernel(
    const float* __restrict__ y, const float* __restrict__ m,
    const float* __restrict__ ln_scale, const float* __restrict__ ln_bias,
    const float* __restrict__ Wout, const float* __restrict__ bout,
    float* __restrict__ dout)
{
  int b = blockIdx.x, j = threadIdx.x;
  __shared__ float lno[256], xh[256], go[128], red2[256], red[4];

  float hv = dout[OFF_NEWH + b*256 + j];
  float s = wave_reduce_sum(hv);
  if ((j & 63) == 0) red[j >> 6] = s;
  __syncthreads();
  float mu = (red[0] + red[1] + red[2] + red[3]) * (1.f/256.f);
  __syncthreads();
  float d = hv - mu;
  float sv = wave_reduce_sum(d*d);
  if ((j & 63) == 0) red[j >> 6] = sv;
  __syncthreads();
  float var = (red[0] + red[1] + red[2] + red[3]) * (1.f/256.f);
  float rstd = rsqrtf(var + 1e-6f);
  float xhj = d * rstd;
  xh[j] = xhj;
  lno[j] = xhj * ln_scale[j] + ln_bias[j];
  __syncthreads();

  // forward o = lno @ Wout + bout, split across thread halves
  int i = j & 127, half = j >> 7;
  float part = half ? 0.f : bout[i];
  #pragma unroll 8
  for (int jj = half*128; jj < half*128 + 128; jj++)
    part = fmaf(lno[jj], Wout[jj*128 + i], part);
  red2[j] = part;
  __syncthreads();
  if (j < 128){
    float o = red2[j] + red2[j + 128];
    float gv = 2.f * m[b*128 + j] * (o - y[b*128 + j]);
    dout[OFF_OUT + b*128 + j] = o;
    dout[OFF_DELTAOUT + b*128 + j] = gv;
    go[j] = gv;
  }
  __syncthreads();

  // backward through Wout and LayerNorm
  float gl = 0.f;
  const float4* wrow = (const float4*)(Wout + j*128);
  #pragma unroll 8
  for (int q = 0; q < 32; q++){
    float4 w = wrow[q];
    gl = fmaf(w.x, go[q*4+0], gl);
    gl = fmaf(w.y, go[q*4+1], gl);
    gl = fmaf(w.z, go[q*4+2], gl);
    gl = fmaf(w.w, go[q*4+3], gl);
  }
  float gx = gl * ln_scale[j];
  __syncthreads();
  float t1 = wave_reduce_sum(gx);
  if ((j & 63) == 0) red[j >> 6] = t1;
  __syncthreads();
  float s1 = (red[0] + red[1] + red[2] + red[3]) * (1.f/256.f);
  __syncthreads();
  float t2 = wave_reduce_sum(gx * xhj);
  if ((j & 63) == 0) red[j >> 6] = t2;
  __syncthreads();
  float s2m = (red[0] + red[1] + red[2] + red[3]) * (1.f/256.f);
  float nid = rstd * (gx - s1 - xhj * s2m);
  dout[OFF_NEWINST + b*256 + j] = nid;
}

// ---------------------------------------------------------------------------
extern "C" void kernel_launch(void* const* d_in, const int* in_sizes, int n_in,
                              void* d_out, int out_size, void* d_ws, size_t ws_size,
                              hipStream_t stream) {
  const float* x          = (const float*)d_in[0];
  const float* y          = (const float*)d_in[1];
  const float* m          = (const float*)d_in[2];
  const float* h          = (const float*)d_in[3];
  const float* delta      = (const float*)d_in[4];
  const float* inst_delta = (const float*)d_in[5];
  const float* prod_jac   = (const float*)d_in[6];
  const float* t          = (const float*)d_in[8];
  const float* Wiz  = (const float*)d_in[9];
  const float* biz  = (const float*)d_in[10];
  const float* Whz  = (const float*)d_in[11];
  const float* Wir  = (const float*)d_in[12];
  const float* bir  = (const float*)d_in[13];
  const float* Whr  = (const float*)d_in[14];
  const float* Win  = (const float*)d_in[15];
  const float* bin_ = (const float*)d_in[16];
  const float* Whn  = (const float*)d_in[17];
  const float* bhn  = (const float*)d_in[18];
  const float* ln_scale = (const float*)d_in[19];
  const float* ln_bias  = (const float*)d_in[20];
  const float* Wout = (const float*)d_in[21];
  const float* bout = (const float*)d_in[22];

  float* dout = (float*)d_out;
  float* ws = (float*)d_ws;

  gates_kernel<<<1024, 256, 0, stream>>>(x, h, t, Wiz, biz, Whz, Wir, bir, Whr,
                                         Win, bin_, Whn, bhn, dout, ws);
  solve_kernel<<<1024, 1024, 0, stream>>>(Whz, Whn, Whr, ws, delta, inst_delta, dout);
  pj_gemm_kernel<<<1024, 512, 0, stream>>>(prod_jac, dout + OFF_JAC,
                                           dout + OFF_NEWPJ, dout + OFF_PJNORM);
  readout_kernel<<<1024, 256, 0, stream>>>(y, m, ln_scale, ln_bias, Wout, bout, dout);
}